// Round 2
// baseline (1218.369 us; speedup 1.0000x reference)
//
#include <hip/hip_runtime.h>
#include <math.h>

typedef _Float16 f16;
typedef _Float16 f16x8 __attribute__((ext_vector_type(8)));
typedef float f32x4 __attribute__((ext_vector_type(4)));

#define MFMA_F16 __builtin_amdgcn_mfma_f32_16x16x32_f16

namespace {
constexpr int kL = 4096;   // faces (queries)
constexpr int kS = 8192;   // edges (keys/values)
constexpr int kD = 256;    // embed dim
constexpr int kH = 2;      // heads
constexpr int kDH = 128;   // head dim
constexpr int kNL = 4;     // layers
constexpr int kNS = 4;     // S-dim splits in dense attention (occupancy)
constexpr float kScale = 0.08838834764831845f;  // 1/sqrt(128)
}

__global__ __launch_bounds__(256) void cvt_f32_f16_k(const float* __restrict__ in,
                                                     f16* __restrict__ out, int n) {
  int i = blockIdx.x * 256 + threadIdx.x;
  int stride = gridDim.x * 256;
  for (; i < n; i += stride) out[i] = (f16)in[i];
}

// Detect the on-device element width of the int "loop" array (int32 vs int64)
// and the bool mask array (1/4/8 bytes per element), purely from the data:
//  - int64 loop: every odd 32-bit word is a zero high-word (values < 2^31).
//  - int32 bool mask: bytes at (i%4)!=0 are all zero.
// flags[0] = loop stride in 32-bit words (1 or 2)
// flags[1] = mask stride in bytes (1, 4, or 8)
__global__ __launch_bounds__(256) void detect_k(const unsigned int* __restrict__ loopw,
                                                const unsigned char* __restrict__ maskb,
                                                int* __restrict__ flags) {
  __shared__ unsigned int s[3];
  if (threadIdx.x < 3) s[threadIdx.x] = 0;
  __syncthreads();
  unsigned int orodd = 0;
  for (int i = 1 + 2 * threadIdx.x; i < 2048; i += 512) orodd |= loopw[i];
  unsigned int nz1 = 0, nz4 = 0;
  for (int i = threadIdx.x; i < 512; i += 256) {
    unsigned char b = maskb[i];
    if ((i & 3) != 0) nz1 |= b;
    if ((i & 7) == 4) nz4 |= b;
  }
  atomicOr(&s[0], orodd);
  atomicOr(&s[1], nz1);
  atomicOr(&s[2], nz4);
  __syncthreads();
  if (threadIdx.x == 0) {
    flags[0] = (s[0] == 0) ? 2 : 1;
    flags[1] = s[1] ? 1 : (s[2] ? 4 : 8);
  }
}

// C[M,N] = A[M,K] @ W[N,K]^T + bias.  Modes:
//  - Kout!=null: KV mode, cols<256 -> Kout[S][256], cols>=256 -> Vt[256][S] and V[S][256]
//  - else: write C16 (fp16 [M][N]) and optionally C32 (f32 [M][N])
__global__ __launch_bounds__(256) void gemm_awt_k(
    const f16* __restrict__ A, const f16* __restrict__ W,
    const float* __restrict__ bias,
    f16* __restrict__ C16, float* __restrict__ C32,
    f16* __restrict__ Kout, f16* __restrict__ VtOut, f16* __restrict__ Vout,
    int M, int N, int K) {
  const int lane = threadIdx.x & 63;
  const int wid = threadIdx.x >> 6;
  const int r = lane & 15, g = lane >> 4;
  const int m0 = blockIdx.x * 64 + (wid >> 1) * 32;
  const int n0 = blockIdx.y * 64 + (wid & 1) * 32;

  f32x4 acc[2][2] = {};
  const f16* ap0 = A + (size_t)(m0 + r) * K + g * 8;
  const f16* ap1 = ap0 + (size_t)16 * K;
  const f16* bp0 = W + (size_t)(n0 + r) * K + g * 8;
  const f16* bp1 = bp0 + (size_t)16 * K;

#pragma unroll 8
  for (int kc = 0; kc < K; kc += 32) {
    f16x8 a0 = *(const f16x8*)(ap0 + kc);
    f16x8 a1 = *(const f16x8*)(ap1 + kc);
    f16x8 b0 = *(const f16x8*)(bp0 + kc);
    f16x8 b1 = *(const f16x8*)(bp1 + kc);
    acc[0][0] = MFMA_F16(a0, b0, acc[0][0], 0, 0, 0);
    acc[0][1] = MFMA_F16(a0, b1, acc[0][1], 0, 0, 0);
    acc[1][0] = MFMA_F16(a1, b0, acc[1][0], 0, 0, 0);
    acc[1][1] = MFMA_F16(a1, b1, acc[1][1], 0, 0, 0);
  }

#pragma unroll
  for (int mt = 0; mt < 2; ++mt)
#pragma unroll
    for (int nt = 0; nt < 2; ++nt) {
      int col = n0 + nt * 16 + r;
      float bv = bias ? bias[col] : 0.0f;
#pragma unroll
      for (int i = 0; i < 4; ++i) {
        int row = m0 + mt * 16 + g * 4 + i;
        float v = acc[mt][nt][i] + bv;
        if (Kout) {
          if (col < 256) {
            Kout[(size_t)row * 256 + col] = (f16)v;
          } else {
            int dv = col - 256;
            VtOut[(size_t)dv * kS + row] = (f16)v;
            Vout[(size_t)row * 256 + dv] = (f16)v;
          }
        } else {
          if (C16) C16[(size_t)row * N + col] = (f16)v;
          if (C32) C32[(size_t)row * N + col] = v;
        }
      }
    }
}

// Dense (un-masked) attention accumulation: num = sum_s exp(q.k*scale) * v,
// den = sum_s exp(q.k*scale), over this block's S-chunk. No max-tracking:
// |scores| <= ~6 so fp32 exp is safe.
__global__ __launch_bounds__(256) void attn_dense_k(
    const f16* __restrict__ Q, const f16* __restrict__ Km,
    const f16* __restrict__ Vt,
    float* __restrict__ numOut, float* __restrict__ denOut) {
  __shared__ __align__(16) f16 P[4][16][72];  // per-wave P tile, padded rows
  const int lane = threadIdx.x & 63;
  const int wid = threadIdx.x >> 6;
  const int r = lane & 15, g = lane >> 4;
  const int h = blockIdx.y;
  const int q0 = blockIdx.x * 64 + wid * 16;
  const int schunk = kS / kNS;
  const int sb0 = blockIdx.z * schunk;

  f16x8 qf[4];
#pragma unroll
  for (int dc = 0; dc < 4; ++dc)
    qf[dc] = *(const f16x8*)(Q + (size_t)(q0 + r) * kD + h * kDH + dc * 32 + g * 8);

  f32x4 o[8] = {};
  float den = 0.0f;

  for (int sb = sb0; sb < sb0 + schunk; sb += 64) {
    // S_tile[16 q][64 keys] = Q . K^T
    f32x4 sf[4] = {};
#pragma unroll
    for (int st = 0; st < 4; ++st) {
      const f16* kr = Km + (size_t)(sb + st * 16 + r) * kD + h * kDH + g * 8;
#pragma unroll
      for (int dc = 0; dc < 4; ++dc) {
        f16x8 kf = *(const f16x8*)(kr + dc * 32);
        sf[st] = MFMA_F16(qf[dc], kf, sf[st], 0, 0, 0);
      }
    }
    // P = exp(S*scale): C-layout (row=(g*4+i), col=st*16+r) -> LDS
#pragma unroll
    for (int st = 0; st < 4; ++st)
#pragma unroll
      for (int i = 0; i < 4; ++i)
        P[wid][g * 4 + i][st * 16 + r] = (f16)__expf(sf[st][i] * kScale);

    // A-layout read back (wave-internal; compiler inserts lgkmcnt)
    f16x8 af0 = *(const f16x8*)(&P[wid][r][g * 8]);
    f16x8 af1 = *(const f16x8*)(&P[wid][r][32 + g * 8]);

    // den: row sums (lane holds 16 of row r's 64 entries; reduce over g)
    float t = 0.0f;
#pragma unroll
    for (int j = 0; j < 8; ++j) t += (float)af0[j] + (float)af1[j];
    t += __shfl_xor(t, 16);
    t += __shfl_xor(t, 32);
    den += t;

    // out += P . V   (V transposed: Vt[head_dim][S] -> contiguous B-frags)
#pragma unroll
    for (int dt = 0; dt < 8; ++dt) {
      const f16* vr = Vt + (size_t)(h * kDH + dt * 16 + r) * kS + sb + g * 8;
      f16x8 v0 = *(const f16x8*)(vr);
      f16x8 v1 = *(const f16x8*)(vr + 32);
      o[dt] = MFMA_F16(af0, v0, o[dt], 0, 0, 0);
      o[dt] = MFMA_F16(af1, v1, o[dt], 0, 0, 0);
    }
  }

  const size_t base = (size_t)(blockIdx.z * kH + h) * kL;
#pragma unroll
  for (int dt = 0; dt < 8; ++dt)
#pragma unroll
    for (int i = 0; i < 4; ++i)
      numOut[(base + q0 + g * 4 + i) * kDH + dt * 16 + r] = o[dt][i];
  if (lane < 16) denOut[base + q0 + lane] = den;
}

// Correction: subtract contributions of the (deduped) loop edges.
// One wave per (face, head). face_mask==false => reference masks nothing
// => no correction. Element widths of loop/mask come from detect_k's flags.
__global__ __launch_bounds__(256) void attn_corr_k(
    const unsigned int* __restrict__ loopw, const unsigned char* __restrict__ maskb,
    const int* __restrict__ flags,
    const f16* __restrict__ Q, const f16* __restrict__ Km,
    const f16* __restrict__ V,
    float* __restrict__ cvec, float* __restrict__ csum) {
  const int lane = threadIdx.x & 63;
  const int wid = threadIdx.x >> 6;
  const int w = blockIdx.x * 4 + wid;  // 0..L*H-1
  const int f = w >> 1, h = w & 1;
  const int lstride = flags[0];  // words per loop element (1=int32, 2=int64)
  const int mstride = flags[1];  // bytes per mask element

  int idx = -1, valid = 0;
  if (lane < 32) {
    idx = (int)loopw[(size_t)(f * 32 + lane) * lstride];  // low word (LE)
    valid = maskb[(size_t)f * mstride] ? 1 : 0;
  }
  // first-occurrence dedupe (reference's scatter-set collapses duplicates)
#pragma unroll
  for (int j = 0; j < 32; ++j) {
    int oidx = __shfl(idx, j);
    if (lane < 32 && j < lane && oidx == idx) valid = 0;
  }

  const size_t qb = (size_t)f * kD + h * kDH + 2 * lane;
  const float qa = (float)Q[qb];
  const float qbv = (float)Q[qb + 1];
  float s0 = 0.0f, cv0 = 0.0f, cv1 = 0.0f;

  for (int e = 0; e < 32; ++e) {
    int ei = __shfl(idx, e);
    int ev = __shfl(valid, e);
    if (!ev) continue;  // wave-uniform
    size_t kb = (size_t)ei * kD + h * kDH + 2 * lane;
    float part = qa * (float)Km[kb] + qbv * (float)Km[kb + 1];
#pragma unroll
    for (int m = 1; m < 64; m <<= 1) part += __shfl_xor(part, m);
    float pe = __expf(part * kScale);
    s0 += pe;
    cv0 += pe * (float)V[kb];
    cv1 += pe * (float)V[kb + 1];
  }
  const size_t base = (size_t)h * kL + f;
  cvec[base * kDH + 2 * lane] = cv0;
  cvec[base * kDH + 2 * lane + 1] = cv1;
  if (lane == 0) csum[base] = s0;
}

// attnout = (num - cvec) / (den - csum), heads re-interleaved to [L][256] fp16
__global__ __launch_bounds__(256) void attn_combine_k(
    const float* __restrict__ num, const float* __restrict__ den,
    const float* __restrict__ cvec, const float* __restrict__ csum,
    f16* __restrict__ out16) {
  int t = blockIdx.x * 256 + threadIdx.x;
  if (t >= kH * kL * kDH) return;
  int d = t & (kDH - 1);
  int fl = t >> 7;
  int f = fl & (kL - 1);
  int h = fl >> 12;
  size_t base = (size_t)h * kL + f;
  float n = -cvec[base * kDH + d];
  float dn = -csum[base];
#pragma unroll
  for (int z = 0; z < kNS; ++z) {
    n += num[((size_t)(z * kH + h) * kL + f) * kDH + d];
    dn += den[(size_t)(z * kH + h) * kL + f];
  }
  out16[(size_t)f * kD + h * kDH + d] = (f16)(n / dn);
}

extern "C" void kernel_launch(void* const* d_in, const int* in_sizes, int n_in,
                              void* d_out, int out_size, void* d_ws, size_t ws_size,
                              hipStream_t stream) {
  const unsigned int* loopw = (const unsigned int*)d_in[0];
  const unsigned char* fmask = (const unsigned char*)d_in[1];
  const float* edge = (const float*)d_in[2];
  const float* face = (const float*)d_in[3];
  const float* inw = (const float*)d_in[4];
  const float* inb = (const float*)d_in[5];
  const float* outw = (const float*)d_in[6];
  const float* outb = (const float*)d_in[7];
  float* out = (float*)d_out;

  char* p = (char*)d_ws;
  auto alloc = [&](size_t bytes) {
    char* q = p;
    p += (bytes + 255) & ~(size_t)255;
    return q;
  };
  int* flags = (int*)alloc(256);
  f16* e16 = (f16*)alloc((size_t)kS * kD * 2);
  f16* win16 = (f16*)alloc((size_t)kNL * 3 * kD * kD * 2);
  f16* wout16 = (f16*)alloc((size_t)kNL * kD * kD * 2);
  f16* xa = (f16*)alloc((size_t)kL * kD * 2);
  f16* xb = (f16*)alloc((size_t)kL * kD * 2);
  f16* q16 = (f16*)alloc((size_t)kL * kD * 2);
  f16* k16 = (f16*)alloc((size_t)kS * kD * 2);
  f16* v16 = (f16*)alloc((size_t)kS * kD * 2);
  f16* vt16 = (f16*)alloc((size_t)kS * kD * 2);
  f16* ao16 = (f16*)alloc((size_t)kL * kD * 2);
  float* numb = (float*)alloc((size_t)kNS * kH * kL * kDH * 4);
  float* denb = (float*)alloc((size_t)kNS * kH * kL * 4);
  float* cvec = (float*)alloc((size_t)kH * kL * kDH * 4);
  float* csum = (float*)alloc((size_t)kH * kL * 4);

  detect_k<<<1, 256, 0, stream>>>(loopw, fmask, flags);
  cvt_f32_f16_k<<<1024, 256, 0, stream>>>(edge, e16, kS * kD);
  cvt_f32_f16_k<<<1024, 256, 0, stream>>>(face, xa, kL * kD);
  cvt_f32_f16_k<<<1024, 256, 0, stream>>>(inw, win16, kNL * 3 * kD * kD);
  cvt_f32_f16_k<<<512, 256, 0, stream>>>(outw, wout16, kNL * kD * kD);

  f16* x = xa;
  f16* xn = xb;
  for (int l = 0; l < kNL; ++l) {
    const f16* wql = win16 + (size_t)l * 3 * kD * kD;
    // Q = x @ wq^T + bq
    gemm_awt_k<<<dim3(kL / 64, kD / 64), 256, 0, stream>>>(
        x, wql, inb + l * 3 * kD, q16, nullptr, nullptr, nullptr, nullptr,
        kL, kD, kD);
    // K,V = edge @ [wk;wv]^T + b  (K row-major, V both row-major and transposed)
    gemm_awt_k<<<dim3(kS / 64, (2 * kD) / 64), 256, 0, stream>>>(
        e16, wql + (size_t)kD * kD, inb + l * 3 * kD + kD, nullptr, nullptr,
        k16, vt16, v16, kS, 2 * kD, kD);
    attn_dense_k<<<dim3(kL / 64, kH, kNS), 256, 0, stream>>>(q16, k16, vt16,
                                                             numb, denb);
    attn_corr_k<<<(kL * kH) / 4, 256, 0, stream>>>(loopw, fmask, flags, q16,
                                                   k16, v16, cvec, csum);
    attn_combine_k<<<(kH * kL * kDH) / 256, 256, 0, stream>>>(numb, denb, cvec,
                                                              csum, ao16);
    // x_next = attnout @ wo^T + bo  (last layer also writes f32 d_out)
    gemm_awt_k<<<dim3(kL / 64, kD / 64), 256, 0, stream>>>(
        ao16, wout16 + (size_t)l * kD * kD, outb + l * kD, xn,
        (l == kNL - 1) ? out : nullptr, nullptr, nullptr, nullptr, kL, kD, kD);
    f16* tmp = x;
    x = xn;
    xn = tmp;
  }
}

// Round 4
// 465.537 us; speedup vs baseline: 2.6171x; 2.6171x over previous
//
#include <hip/hip_runtime.h>
#include <math.h>

typedef _Float16 f16;
typedef _Float16 f16x4 __attribute__((ext_vector_type(4)));
typedef _Float16 f16x8 __attribute__((ext_vector_type(8)));
typedef float f32x4 __attribute__((ext_vector_type(4)));

#define MFMA_F16 __builtin_amdgcn_mfma_f32_16x16x32_f16

namespace {
constexpr int kL = 4096;   // faces (queries)
constexpr int kS = 8192;   // edges (keys/values)
constexpr int kD = 256;    // embed dim
constexpr int kH = 2;      // heads
constexpr int kDH = 128;   // head dim
constexpr int kNL = 4;     // layers
constexpr int kNS = 8;     // S-dim splits in dense attention (occupancy)
constexpr float kScale = 0.08838834764831845f;  // 1/sqrt(128)
}

__global__ __launch_bounds__(256) void cvt_f32_f16_k(const float* __restrict__ in,
                                                     f16* __restrict__ out, int n) {
  int i = blockIdx.x * 256 + threadIdx.x;
  int stride = gridDim.x * 256;
  for (; i < n; i += stride) out[i] = (f16)in[i];
}

// Detect on-device element widths of loop (int32/int64) and mask (1/4/8 B).
__global__ __launch_bounds__(256) void detect_k(const unsigned int* __restrict__ loopw,
                                                const unsigned char* __restrict__ maskb,
                                                int* __restrict__ flags) {
  __shared__ unsigned int s[3];
  if (threadIdx.x < 3) s[threadIdx.x] = 0;
  __syncthreads();
  unsigned int orodd = 0;
  for (int i = 1 + 2 * threadIdx.x; i < 2048; i += 512) orodd |= loopw[i];
  unsigned int nz1 = 0, nz4 = 0;
  for (int i = threadIdx.x; i < 512; i += 256) {
    unsigned char b = maskb[i];
    if ((i & 3) != 0) nz1 |= b;
    if ((i & 7) == 4) nz4 |= b;
  }
  atomicOr(&s[0], orodd);
  atomicOr(&s[1], nz1);
  atomicOr(&s[2], nz4);
  __syncthreads();
  if (threadIdx.x == 0) {
    flags[0] = (s[0] == 0) ? 2 : 1;
    flags[1] = s[1] ? 1 : (s[2] ? 4 : 8);
  }
}

// C[M,N] = A[M,K] @ W[N,K]^T + bias.
__global__ __launch_bounds__(256) void gemm_awt_k(
    const f16* __restrict__ A, const f16* __restrict__ W,
    const float* __restrict__ bias,
    f16* __restrict__ C16, float* __restrict__ C32,
    f16* __restrict__ Kout, f16* __restrict__ VtOut, f16* __restrict__ Vout,
    int M, int N, int K) {
  const int lane = threadIdx.x & 63;
  const int wid = threadIdx.x >> 6;
  const int r = lane & 15, g = lane >> 4;
  const int m0 = blockIdx.x * 64 + (wid >> 1) * 32;
  const int n0 = blockIdx.y * 64 + (wid & 1) * 32;

  f32x4 acc[2][2] = {};
  const f16* ap0 = A + (size_t)(m0 + r) * K + g * 8;
  const f16* ap1 = ap0 + (size_t)16 * K;
  const f16* bp0 = W + (size_t)(n0 + r) * K + g * 8;
  const f16* bp1 = bp0 + (size_t)16 * K;

#pragma unroll 8
  for (int kc = 0; kc < K; kc += 32) {
    f16x8 a0 = *(const f16x8*)(ap0 + kc);
    f16x8 a1 = *(const f16x8*)(ap1 + kc);
    f16x8 b0 = *(const f16x8*)(bp0 + kc);
    f16x8 b1 = *(const f16x8*)(bp1 + kc);
    acc[0][0] = MFMA_F16(a0, b0, acc[0][0], 0, 0, 0);
    acc[0][1] = MFMA_F16(a0, b1, acc[0][1], 0, 0, 0);
    acc[1][0] = MFMA_F16(a1, b0, acc[1][0], 0, 0, 0);
    acc[1][1] = MFMA_F16(a1, b1, acc[1][1], 0, 0, 0);
  }

#pragma unroll
  for (int mt = 0; mt < 2; ++mt)
#pragma unroll
    for (int nt = 0; nt < 2; ++nt) {
      int col = n0 + nt * 16 + r;
      float bv = bias ? bias[col] : 0.0f;
#pragma unroll
      for (int i = 0; i < 4; ++i) {
        int row = m0 + mt * 16 + g * 4 + i;
        float v = acc[mt][nt][i] + bv;
        if (Kout) {
          if (col < 256) {
            Kout[(size_t)row * 256 + col] = (f16)v;
          } else {
            int dv = col - 256;
            VtOut[(size_t)dv * kS + row] = (f16)v;
            Vout[(size_t)row * 256 + dv] = (f16)v;
          }
        } else {
          if (C16) C16[(size_t)row * N + col] = (f16)v;
          if (C32) C32[(size_t)row * N + col] = v;
        }
      }
    }
}

// Dense attention: LDS-staged K/V tiles shared by 4 waves, 32 q/wave.
// K tile rows are permuted by mu(m)=((m&15)<<2)|(m>>4) so the P transpose
// packs as b64 writes while V^T stages unpermuted (mu = m^-1 cancels).
// All LDS rows XOR-swizzled (slot ^ row&7) -> <=2-way bank access.
__global__ __launch_bounds__(256, 2) void attn_dense2_k(
    const f16* __restrict__ Q, const f16* __restrict__ Km,
    const f16* __restrict__ Vt,
    f16* __restrict__ numOut, float* __restrict__ denOut) {
  __shared__ __align__(16) f16 Kl[2][64 * 128];   // [key-row m][d], swizzled
  __shared__ __align__(16) f16 Vl[2][128 * 64];   // [d][key c], swizzled
  __shared__ __align__(16) f16 Pl[4][32 * 64];    // per-wave [q][c], swizzled
  const int tid = threadIdx.x;
  const int lane = tid & 63, wid = tid >> 6;
  const int r = lane & 15, g = lane >> 4;
  const int h = blockIdx.y;
  const int q0w = blockIdx.x * 128 + wid * 32;
  const int sb0 = blockIdx.z * (kS / kNS);
  const int nt = (kS / kNS) / 64;

  // Q fragments: 32 q per wave, held in registers
  f16x8 qf[2][4];
#pragma unroll
  for (int qr = 0; qr < 2; ++qr)
#pragma unroll
    for (int dc = 0; dc < 4; ++dc)
      qf[qr][dc] = *(const f16x8*)(Q + (size_t)(q0w + qr * 16 + r) * kD +
                                   h * kDH + dc * 32 + g * 8);

  // staging addresses (element offsets), advance per step
  int kSrc[4], kDst[4], vSrc[4], vDst[4];
#pragma unroll
  for (int p = 0; p < 4; ++p) {
    int ci = p * 64 + lane;
    int m = wid * 16 + (ci >> 4), s = ci & 15;
    int mu = ((m & 15) << 2) | (m >> 4);
    kSrc[p] = (sb0 + mu) * kD + h * kDH + 8 * (s ^ (m & 7));
    kDst[p] = m * 128 + 8 * s;
    int cv = p * 256 + tid;
    int d = cv >> 3, sv = cv & 7;
    vSrc[p] = (h * kDH + d) * kS + sb0 + 8 * (sv ^ (d & 7));
    vDst[p] = d * 64 + 8 * sv;
  }

  f32x4 o[2][8] = {};
  float den[2] = {0.0f, 0.0f};
  f16x8 kst[4], vst[4];

  // prologue: stage tile 0
#pragma unroll
  for (int p = 0; p < 4; ++p) {
    kst[p] = *(const f16x8*)(Km + kSrc[p]);
    vst[p] = *(const f16x8*)(Vt + vSrc[p]);
  }
#pragma unroll
  for (int p = 0; p < 4; ++p) {
    *(f16x8*)&Kl[0][kDst[p]] = kst[p];
    *(f16x8*)&Vl[0][vDst[p]] = vst[p];
  }
  __syncthreads();

  for (int t = 0; t < nt; ++t) {
    const int cur = t & 1;
    if (t + 1 < nt) {  // issue next-tile loads early (hide under compute)
#pragma unroll
      for (int p = 0; p < 4; ++p) {
        kst[p] = *(const f16x8*)(Km + kSrc[p] + (t + 1) * 64 * kD);
        vst[p] = *(const f16x8*)(Vt + vSrc[p] + (t + 1) * 64);
      }
    }

    // QK^T: 32 mfma, B-frags from swizzled Kl
    f32x4 sf[2][4] = {};
#pragma unroll
    for (int st = 0; st < 4; ++st) {
      int m = st * 16 + r;
#pragma unroll
      for (int dc = 0; dc < 4; ++dc) {
        f16x8 kf = *(const f16x8*)&Kl[cur][m * 128 + 8 * ((dc * 4 + g) ^ (m & 7))];
        sf[0][st] = MFMA_F16(qf[0][dc], kf, sf[0][st], 0, 0, 0);
        sf[1][st] = MFMA_F16(qf[1][dc], kf, sf[1][st], 0, 0, 0);
      }
    }

    // P = exp(S*scale) -> packed b64 stores into per-wave Pl
#pragma unroll
    for (int qr = 0; qr < 2; ++qr)
#pragma unroll
      for (int i = 0; i < 4; ++i) {
        int q = qr * 16 + g * 4 + i;
        f16x4 pv;
        pv[0] = (f16)__expf(sf[qr][0][i] * kScale);
        pv[1] = (f16)__expf(sf[qr][1][i] * kScale);
        pv[2] = (f16)__expf(sf[qr][2][i] * kScale);
        pv[3] = (f16)__expf(sf[qr][3][i] * kScale);
        *(f16x4*)&Pl[wid][q * 64 + ((4 * r) ^ ((q & 7) << 3))] = pv;
      }

    // read P back as A-frags; den from the same regs
    f16x8 pa[2][2];
#pragma unroll
    for (int qr = 0; qr < 2; ++qr) {
      int q = qr * 16 + r;
      pa[qr][0] = *(const f16x8*)&Pl[wid][q * 64 + ((8 * g) ^ ((q & 7) << 3))];
      pa[qr][1] = *(const f16x8*)&Pl[wid][q * 64 + ((32 + 8 * g) ^ ((q & 7) << 3))];
      float ts = 0.0f;
#pragma unroll
      for (int j = 0; j < 8; ++j) ts += (float)pa[qr][0][j] + (float)pa[qr][1][j];
      ts += __shfl_xor(ts, 16);
      ts += __shfl_xor(ts, 32);
      den[qr] += ts;
    }

    // PV: 32 mfma, B-frags from swizzled Vl (shared across qr)
#pragma unroll
    for (int dt = 0; dt < 8; ++dt) {
      int d = dt * 16 + r;
      f16x8 v0 = *(const f16x8*)&Vl[cur][d * 64 + 8 * (g ^ (d & 7))];
      f16x8 v1 = *(const f16x8*)&Vl[cur][d * 64 + 8 * ((4 + g) ^ (d & 7))];
#pragma unroll
      for (int qr = 0; qr < 2; ++qr) {
        o[qr][dt] = MFMA_F16(pa[qr][0], v0, o[qr][dt], 0, 0, 0);
        o[qr][dt] = MFMA_F16(pa[qr][1], v1, o[qr][dt], 0, 0, 0);
      }
    }

    // write next tile (other buffer; prev-iter barrier made it safe)
    if (t + 1 < nt) {
      const int nxt = cur ^ 1;
#pragma unroll
      for (int p = 0; p < 4; ++p) {
        *(f16x8*)&Kl[nxt][kDst[p]] = kst[p];
        *(f16x8*)&Vl[nxt][vDst[p]] = vst[p];
      }
      __syncthreads();
    }
  }

  const size_t base = (size_t)(blockIdx.z * kH + h) * kL + q0w;
#pragma unroll
  for (int qr = 0; qr < 2; ++qr)
#pragma unroll
    for (int dt = 0; dt < 8; ++dt)
#pragma unroll
      for (int i = 0; i < 4; ++i)
        numOut[(base + qr * 16 + g * 4 + i) * kDH + dt * 16 + r] = (f16)o[qr][dt][i];
  if (g == 0) {
    denOut[base + r] = den[0];
    denOut[base + 16 + r] = den[1];
  }
}

// Correction: subtract contributions of the (deduped) loop edges.
__global__ __launch_bounds__(256) void attn_corr_k(
    const unsigned int* __restrict__ loopw, const unsigned char* __restrict__ maskb,
    const int* __restrict__ flags,
    const f16* __restrict__ Q, const f16* __restrict__ Km,
    const f16* __restrict__ V,
    float* __restrict__ cvec, float* __restrict__ csum) {
  const int lane = threadIdx.x & 63;
  const int wid = threadIdx.x >> 6;
  const int w = blockIdx.x * 4 + wid;  // 0..L*H-1
  const int f = w >> 1, h = w & 1;
  const int lstride = flags[0];
  const int mstride = flags[1];

  int idx = -1, valid = 0;
  if (lane < 32) {
    idx = (int)loopw[(size_t)(f * 32 + lane) * lstride];
    valid = maskb[(size_t)f * mstride] ? 1 : 0;
  }
#pragma unroll
  for (int j = 0; j < 32; ++j) {
    int oidx = __shfl(idx, j);
    if (lane < 32 && j < lane && oidx == idx) valid = 0;
  }

  const size_t qb = (size_t)f * kD + h * kDH + 2 * lane;
  const float qa = (float)Q[qb];
  const float qbv = (float)Q[qb + 1];
  float s0 = 0.0f, cv0 = 0.0f, cv1 = 0.0f;

  for (int e = 0; e < 32; ++e) {
    int ei = __shfl(idx, e);
    int ev = __shfl(valid, e);
    if (!ev) continue;
    size_t kb = (size_t)ei * kD + h * kDH + 2 * lane;
    float part = qa * (float)Km[kb] + qbv * (float)Km[kb + 1];
#pragma unroll
    for (int m = 1; m < 64; m <<= 1) part += __shfl_xor(part, m);
    float pe = __expf(part * kScale);
    s0 += pe;
    cv0 += pe * (float)V[kb];
    cv1 += pe * (float)V[kb + 1];
  }
  const size_t base = (size_t)h * kL + f;
  cvec[base * kDH + 2 * lane] = cv0;
  cvec[base * kDH + 2 * lane + 1] = cv1;
  if (lane == 0) csum[base] = s0;
}

// attnout = (num - cvec) / (den - csum), heads re-interleaved to [L][256] fp16
__global__ __launch_bounds__(256) void attn_combine_k(
    const f16* __restrict__ num, const float* __restrict__ den,
    const float* __restrict__ cvec, const float* __restrict__ csum,
    f16* __restrict__ out16) {
  int t = blockIdx.x * 256 + threadIdx.x;
  if (t >= kH * kL * kDH) return;
  int d = t & (kDH - 1);
  int fl = t >> 7;
  int f = fl & (kL - 1);
  int h = fl >> 12;
  size_t base = (size_t)h * kL + f;
  float n = -cvec[base * kDH + d];
  float dn = -csum[base];
#pragma unroll
  for (int z = 0; z < kNS; ++z) {
    n += (float)num[((size_t)(z * kH + h) * kL + f) * kDH + d];
    dn += den[(size_t)(z * kH + h) * kL + f];
  }
  out16[(size_t)f * kD + h * kDH + d] = (f16)(n / dn);
}

extern "C" void kernel_launch(void* const* d_in, const int* in_sizes, int n_in,
                              void* d_out, int out_size, void* d_ws, size_t ws_size,
                              hipStream_t stream) {
  const unsigned int* loopw = (const unsigned int*)d_in[0];
  const unsigned char* fmask = (const unsigned char*)d_in[1];
  const float* edge = (const float*)d_in[2];
  const float* face = (const float*)d_in[3];
  const float* inw = (const float*)d_in[4];
  const float* inb = (const float*)d_in[5];
  const float* outw = (const float*)d_in[6];
  const float* outb = (const float*)d_in[7];
  float* out = (float*)d_out;

  char* p = (char*)d_ws;
  auto alloc = [&](size_t bytes) {
    char* q = p;
    p += (bytes + 255) & ~(size_t)255;
    return q;
  };
  int* flags = (int*)alloc(256);
  f16* e16 = (f16*)alloc((size_t)kS * kD * 2);
  f16* win16 = (f16*)alloc((size_t)kNL * 3 * kD * kD * 2);
  f16* wout16 = (f16*)alloc((size_t)kNL * kD * kD * 2);
  f16* xa = (f16*)alloc((size_t)kL * kD * 2);
  f16* xb = (f16*)alloc((size_t)kL * kD * 2);
  f16* q16 = (f16*)alloc((size_t)kL * kD * 2);
  f16* k16 = (f16*)alloc((size_t)kS * kD * 2);
  f16* v16 = (f16*)alloc((size_t)kS * kD * 2);
  f16* vt16 = (f16*)alloc((size_t)kS * kD * 2);
  f16* ao16 = (f16*)alloc((size_t)kL * kD * 2);
  f16* numb = (f16*)alloc((size_t)kNS * kH * kL * kDH * 2);
  float* denb = (float*)alloc((size_t)kNS * kH * kL * 4);
  float* cvec = (float*)alloc((size_t)kH * kL * kDH * 4);
  float* csum = (float*)alloc((size_t)kH * kL * 4);

  detect_k<<<1, 256, 0, stream>>>(loopw, fmask, flags);
  cvt_f32_f16_k<<<1024, 256, 0, stream>>>(edge, e16, kS * kD);
  cvt_f32_f16_k<<<1024, 256, 0, stream>>>(face, xa, kL * kD);
  cvt_f32_f16_k<<<1024, 256, 0, stream>>>(inw, win16, kNL * 3 * kD * kD);
  cvt_f32_f16_k<<<512, 256, 0, stream>>>(outw, wout16, kNL * kD * kD);

  f16* x = xa;
  f16* xn = xb;
  for (int l = 0; l < kNL; ++l) {
    const f16* wql = win16 + (size_t)l * 3 * kD * kD;
    gemm_awt_k<<<dim3(kL / 64, kD / 64), 256, 0, stream>>>(
        x, wql, inb + l * 3 * kD, q16, nullptr, nullptr, nullptr, nullptr,
        kL, kD, kD);
    gemm_awt_k<<<dim3(kS / 64, (2 * kD) / 64), 256, 0, stream>>>(
        e16, wql + (size_t)kD * kD, inb + l * 3 * kD + kD, nullptr, nullptr,
        k16, vt16, v16, kS, 2 * kD, kD);
    attn_dense2_k<<<dim3(kL / 128, kH, kNS), 256, 0, stream>>>(q16, k16, vt16,
                                                               numb, denb);
    attn_corr_k<<<(kL * kH) / 4, 256, 0, stream>>>(loopw, fmask, flags, q16,
                                                   k16, v16, cvec, csum);
    attn_combine_k<<<(kH * kL * kDH) / 256, 256, 0, stream>>>(numb, denb, cvec,
                                                              csum, ao16);
    gemm_awt_k<<<dim3(kL / 64, kD / 64), 256, 0, stream>>>(
        ao16, wout16 + (size_t)l * kD * kD, outb + l * kD, xn,
        (l == kNL - 1) ? out : nullptr, nullptr, nullptr, nullptr, kL, kD, kD);
    f16* tmp = x;
    x = xn;
    xn = tmp;
  }
}

// Round 5
// 434.397 us; speedup vs baseline: 2.8047x; 1.0717x over previous
//
#include <hip/hip_runtime.h>
#include <math.h>

typedef _Float16 f16;
typedef _Float16 f16x4 __attribute__((ext_vector_type(4)));
typedef _Float16 f16x8 __attribute__((ext_vector_type(8)));
typedef float f32x4 __attribute__((ext_vector_type(4)));
typedef float f32x16 __attribute__((ext_vector_type(16)));

#define MFMA_F16 __builtin_amdgcn_mfma_f32_16x16x32_f16
#define MFMA32_F16 __builtin_amdgcn_mfma_f32_32x32x16_f16

namespace {
constexpr int kL = 4096;   // faces (queries)
constexpr int kS = 8192;   // edges (keys/values)
constexpr int kD = 256;    // embed dim
constexpr int kH = 2;      // heads
constexpr int kDH = 128;   // head dim
constexpr int kNL = 4;     // layers
constexpr int kNS = 8;     // S-dim splits in dense attention
constexpr float kScale = 0.08838834764831845f;  // 1/sqrt(128)
}

// ---------- fused f32->f16 conversion of all inputs (one dispatch) ----------
__global__ __launch_bounds__(256) void cvt_all_k(
    const float* __restrict__ edge, const float* __restrict__ face,
    const float* __restrict__ inw, const float* __restrict__ outw,
    f16* __restrict__ e16, f16* __restrict__ xa,
    f16* __restrict__ win16, f16* __restrict__ wout16) {
  // vec4 regions: edge 524288 | face 262144 | inw 196608 | outw 65536
  for (int i = blockIdx.x * 256 + threadIdx.x; i < 1048576; i += 1024 * 256) {
    const float* src;
    f16* dst;
    int off;
    if (i < 524288) { src = edge; dst = e16; off = i; }
    else if (i < 786432) { src = face; dst = xa; off = i - 524288; }
    else if (i < 983040) { src = inw; dst = win16; off = i - 786432; }
    else { src = outw; dst = wout16; off = i - 983040; }
    float4 v = *(const float4*)(src + 4 * (size_t)off);
    f16x4 h;
    h[0] = (f16)v.x; h[1] = (f16)v.y; h[2] = (f16)v.z; h[3] = (f16)v.w;
    *(f16x4*)(dst + 4 * (size_t)off) = h;
  }
}

// Detect on-device element widths of loop (int32/int64) and mask (1/4/8 B).
__global__ __launch_bounds__(256) void detect_k(const unsigned int* __restrict__ loopw,
                                                const unsigned char* __restrict__ maskb,
                                                int* __restrict__ flags) {
  __shared__ unsigned int s[3];
  if (threadIdx.x < 3) s[threadIdx.x] = 0;
  __syncthreads();
  unsigned int orodd = 0;
  for (int i = 1 + 2 * threadIdx.x; i < 2048; i += 512) orodd |= loopw[i];
  unsigned int nz1 = 0, nz4 = 0;
  for (int i = threadIdx.x; i < 512; i += 256) {
    unsigned char b = maskb[i];
    if ((i & 3) != 0) nz1 |= b;
    if ((i & 7) == 4) nz4 |= b;
  }
  atomicOr(&s[0], orodd);
  atomicOr(&s[1], nz1);
  atomicOr(&s[2], nz4);
  __syncthreads();
  if (threadIdx.x == 0) {
    flags[0] = (s[0] == 0) ? 2 : 1;
    flags[1] = s[1] ? 1 : (s[2] ? 4 : 8);
  }
}

// ---------- GEMM core: 64x64 tile, A[M,K] @ W[N,K]^T ----------
__device__ __forceinline__ void gemm_core(const f16* __restrict__ A,
                                          const f16* __restrict__ W, int K,
                                          int m0, int n0, int r, int g,
                                          f32x4 acc[2][2]) {
  const f16* ap0 = A + (size_t)(m0 + r) * K + g * 8;
  const f16* ap1 = ap0 + (size_t)16 * K;
  const f16* bp0 = W + (size_t)(n0 + r) * K + g * 8;
  const f16* bp1 = bp0 + (size_t)16 * K;
#pragma unroll 8
  for (int kc = 0; kc < K; kc += 32) {
    f16x8 a0 = *(const f16x8*)(ap0 + kc);
    f16x8 a1 = *(const f16x8*)(ap1 + kc);
    f16x8 b0 = *(const f16x8*)(bp0 + kc);
    f16x8 b1 = *(const f16x8*)(bp1 + kc);
    acc[0][0] = MFMA_F16(a0, b0, acc[0][0], 0, 0, 0);
    acc[0][1] = MFMA_F16(a0, b1, acc[0][1], 0, 0, 0);
    acc[1][0] = MFMA_F16(a1, b0, acc[1][0], 0, 0, 0);
    acc[1][1] = MFMA_F16(a1, b1, acc[1][1], 0, 0, 0);
  }
}

// Fused Q/K/V projection: bid<256 -> Q = x@wq^T (N=256) ; else KV = e@[wk;wv]^T
__global__ __launch_bounds__(256) void qkv_gemm_k(
    const f16* __restrict__ x, const f16* __restrict__ e16,
    const f16* __restrict__ wql, const float* __restrict__ biasl,
    f16* __restrict__ q16, f16* __restrict__ k16,
    f16* __restrict__ vt16, f16* __restrict__ v16) {
  const int lane = threadIdx.x & 63;
  const int wid = threadIdx.x >> 6;
  const int r = lane & 15, g = lane >> 4;
  const int bid = blockIdx.x;
  const bool qmode = bid < 256;
  int bx, by;
  const f16* A;
  const f16* W;
  const float* bias;
  if (qmode) {
    bx = bid & 63; by = bid >> 6;
    A = x; W = wql; bias = biasl;
  } else {
    int t = bid - 256;
    bx = t & 127; by = t >> 7;
    A = e16; W = wql + (size_t)kD * kD; bias = biasl + kD;
  }
  const int m0 = bx * 64 + (wid >> 1) * 32;
  const int n0 = by * 64 + (wid & 1) * 32;
  f32x4 acc[2][2] = {};
  gemm_core(A, W, kD, m0, n0, r, g, acc);

#pragma unroll
  for (int mt = 0; mt < 2; ++mt)
#pragma unroll
    for (int nt = 0; nt < 2; ++nt) {
      int col = n0 + nt * 16 + r;
      float bv = bias[col];
#pragma unroll
      for (int i = 0; i < 4; ++i) {
        int row = m0 + mt * 16 + g * 4 + i;
        float v = acc[mt][nt][i] + bv;
        if (qmode) {
          q16[(size_t)row * kD + col] = (f16)v;
        } else if (col < 256) {
          k16[(size_t)row * 256 + col] = (f16)v;
        } else {
          int dv = col - 256;
          vt16[(size_t)dv * kS + row] = (f16)v;
          v16[(size_t)row * 256 + dv] = (f16)v;
        }
      }
    }
}

// Out-projection: C = A @ W^T + bias -> fp16 (and optionally f32 final out)
__global__ __launch_bounds__(256) void gemm_awt_k(
    const f16* __restrict__ A, const f16* __restrict__ W,
    const float* __restrict__ bias, f16* __restrict__ C16,
    float* __restrict__ C32, int M, int N, int K) {
  const int lane = threadIdx.x & 63;
  const int wid = threadIdx.x >> 6;
  const int r = lane & 15, g = lane >> 4;
  const int m0 = blockIdx.x * 64 + (wid >> 1) * 32;
  const int n0 = blockIdx.y * 64 + (wid & 1) * 32;
  f32x4 acc[2][2] = {};
  gemm_core(A, W, K, m0, n0, r, g, acc);
#pragma unroll
  for (int mt = 0; mt < 2; ++mt)
#pragma unroll
    for (int nt = 0; nt < 2; ++nt) {
      int col = n0 + nt * 16 + r;
      float bv = bias[col];
#pragma unroll
      for (int i = 0; i < 4; ++i) {
        int row = m0 + mt * 16 + g * 4 + i;
        float v = acc[mt][nt][i] + bv;
        C16[(size_t)row * N + col] = (f16)v;
        if (C32) C32[(size_t)row * N + col] = v;
      }
    }
}

// ---------- dense attention, 32x32x16 MFMA, in-register P ----------
__device__ __forceinline__ unsigned pkh(float a, float b) {
  auto h2 = __builtin_amdgcn_cvt_pkrtz(a, b);
  return __builtin_bit_cast(unsigned, h2);
}
__device__ __forceinline__ void pswap(unsigned a, unsigned b, unsigned& x,
                                      unsigned& y) {
  typedef int i32x2 __attribute__((ext_vector_type(2)));
  i32x2 rr = __builtin_amdgcn_permlane32_swap((int)a, (int)b, false, false);
  x = (unsigned)rr[0];
  y = (unsigned)rr[1];
}
// Build P^T B-frag (16 keys) from 8 per-lane exp values (see round-4 notes):
// word0,word2 = swap(pk(p0,p1), pk(p4,p5)); word1,word3 = swap(pk(p2,p3), pk(p6,p7))
__device__ __forceinline__ f16x8 build_pfrag(float p0, float p1, float p2,
                                             float p3, float p4, float p5,
                                             float p6, float p7) {
  unsigned a0 = pkh(p0, p1), b0 = pkh(p4, p5);
  unsigned a1 = pkh(p2, p3), b1 = pkh(p6, p7);
  unsigned w0, w1, w2, w3;
  pswap(a0, b0, w0, w2);
  pswap(a1, b1, w1, w3);
  union { unsigned u[4]; f16x8 v; } r;
  r.u[0] = w0; r.u[1] = w1; r.u[2] = w2; r.u[3] = w3;
  return r.v;
}

// S^T = mfma(K, Q^T): lane holds scores for q=lane&31 -> exp in-register ->
// P^T B-frags via cvt_pkrtz + permlane32_swap (no P LDS). PV: out^T = V^T P^T.
__global__ __launch_bounds__(256, 2) void attn_dense3_k(
    const f16* __restrict__ Q, const f16* __restrict__ Km,
    const f16* __restrict__ Vt,
    f16* __restrict__ numOut, float* __restrict__ denOut) {
  __shared__ __align__(16) f16 Kl[2][64 * 128];  // [key][d], XOR-swizzled
  __shared__ __align__(16) f16 Vl[2][128 * 64];  // [d][key], XOR-swizzled
  const int tid = threadIdx.x;
  const int lane = tid & 63, wid = tid >> 6;
  const int la = lane & 31, hi = lane >> 5;
  const int h = blockIdx.y;
  const int q0w = blockIdx.x * 128 + wid * 32;
  const int sb0 = blockIdx.z * (kS / kNS);
  const int nt = (kS / kNS) / 64;

  // Q B-frags: col=lane&31=q, k=(lane>>5)*8+j  (8 frags cover d=128)
  f16x8 qb[8];
#pragma unroll
  for (int kk = 0; kk < 8; ++kk)
    qb[kk] = *(const f16x8*)(Q + (size_t)(q0w + la) * kD + h * kDH + kk * 16 +
                             hi * 8);

  // staging addresses (pre-swizzled sources, linear-in-row LDS dests)
  int kSrc[4], kDst[4], vSrc[4], vDst[4];
#pragma unroll
  for (int p = 0; p < 4; ++p) {
    int m = wid * 16 + p * 4 + (lane >> 4);
    int s = lane & 15;
    kSrc[p] = (sb0 + m) * kD + h * kDH + 8 * (s ^ (m & 7));
    kDst[p] = m * 128 + 8 * s;
    int cv = p * 256 + tid;
    int d = cv >> 3, sv = cv & 7;
    vSrc[p] = (h * kDH + d) * kS + sb0 + 8 * (sv ^ (d & 7));
    vDst[p] = d * 64 + 8 * sv;
  }

  f32x16 o0 = {}, o1 = {}, o2 = {}, o3 = {};
  float den = 0.0f;
  f16x8 kst[4], vst[4];

#pragma unroll
  for (int p = 0; p < 4; ++p) {
    kst[p] = *(const f16x8*)(Km + kSrc[p]);
    vst[p] = *(const f16x8*)(Vt + vSrc[p]);
  }
#pragma unroll
  for (int p = 0; p < 4; ++p) {
    *(f16x8*)&Kl[0][kDst[p]] = kst[p];
    *(f16x8*)&Vl[0][vDst[p]] = vst[p];
  }
  __syncthreads();

  for (int t = 0; t < nt; ++t) {
    const int cur = t & 1;
    if (t + 1 < nt) {
#pragma unroll
      for (int p = 0; p < 4; ++p) {
        kst[p] = *(const f16x8*)(Km + kSrc[p] + (t + 1) * 64 * kD);
        vst[p] = *(const f16x8*)(Vt + vSrc[p] + (t + 1) * 64);
      }
    }

    // QK^T (swapped): st[kt] = K[kt]-tile . Q^T ; C cols = q
    f32x16 st0 = {}, st1 = {};
#pragma unroll
    for (int kk = 0; kk < 8; ++kk) {
      int sl = 8 * ((kk * 2 + hi) ^ (la & 7));
      f16x8 k0 = *(const f16x8*)&Kl[cur][la * 128 + sl];
      f16x8 k1 = *(const f16x8*)&Kl[cur][(32 + la) * 128 + sl];
      st0 = MFMA32_F16(k0, qb[kk], st0, 0, 0, 0);
      st1 = MFMA32_F16(k1, qb[kk], st1, 0, 0, 0);
    }

    // exp in-register
    f32x16 pe0, pe1;
#pragma unroll
    for (int i = 0; i < 16; ++i) {
      pe0[i] = __expf(st0[i] * kScale);
      pe1[i] = __expf(st1[i] * kScale);
    }
#pragma unroll
    for (int i = 0; i < 16; ++i) den += pe0[i] + pe1[i];

    // P^T B-frags (4 x 16 keys)
    f16x8 pf[4];
    pf[0] = build_pfrag(pe0[0], pe0[1], pe0[2], pe0[3], pe0[4], pe0[5], pe0[6], pe0[7]);
    pf[1] = build_pfrag(pe0[8], pe0[9], pe0[10], pe0[11], pe0[12], pe0[13], pe0[14], pe0[15]);
    pf[2] = build_pfrag(pe1[0], pe1[1], pe1[2], pe1[3], pe1[4], pe1[5], pe1[6], pe1[7]);
    pf[3] = build_pfrag(pe1[8], pe1[9], pe1[10], pe1[11], pe1[12], pe1[13], pe1[14], pe1[15]);

    // PV: out^T[d][q] += V^T-frag . P^T-frag
#pragma unroll
    for (int dt = 0; dt < 4; ++dt) {
      int d = dt * 32 + la;
      f32x16* op = (dt == 0) ? &o0 : (dt == 1) ? &o1 : (dt == 2) ? &o2 : &o3;
#pragma unroll
      for (int ks = 0; ks < 4; ++ks) {
        f16x8 vf = *(const f16x8*)&Vl[cur][d * 64 + 8 * ((ks * 2 + hi) ^ (d & 7))];
        *op = MFMA32_F16(vf, pf[ks], *op, 0, 0, 0);
      }
    }

    if (t + 1 < nt) {
      const int nxt = cur ^ 1;
#pragma unroll
      for (int p = 0; p < 4; ++p) {
        *(f16x8*)&Kl[nxt][kDst[p]] = kst[p];
        *(f16x8*)&Vl[nxt][vDst[p]] = vst[p];
      }
      __syncthreads();
    }
  }

  const size_t base = ((size_t)blockIdx.z * kH + h) * kL + q0w;
#pragma unroll
  for (int dt = 0; dt < 4; ++dt) {
    const f32x16* op = (dt == 0) ? &o0 : (dt == 1) ? &o1 : (dt == 2) ? &o2 : &o3;
#pragma unroll
    for (int gq = 0; gq < 4; ++gq) {
      int d0 = dt * 32 + gq * 8 + 4 * hi;
      f16x4 w;
      w[0] = (f16)(*op)[4 * gq + 0];
      w[1] = (f16)(*op)[4 * gq + 1];
      w[2] = (f16)(*op)[4 * gq + 2];
      w[3] = (f16)(*op)[4 * gq + 3];
      *(f16x4*)&numOut[(base + la) * kDH + d0] = w;
    }
  }
  float dq = den + __shfl_xor(den, 32);
  if (lane < 32) denOut[base + lane] = dq;
}

// ---------- fused correction + combine ----------
__global__ __launch_bounds__(256) void corrcomb_k(
    const unsigned int* __restrict__ loopw, const unsigned char* __restrict__ maskb,
    const int* __restrict__ flags,
    const f16* __restrict__ Q, const f16* __restrict__ Km,
    const f16* __restrict__ V,
    const f16* __restrict__ numb, const float* __restrict__ denb,
    f16* __restrict__ out16) {
  __shared__ float cvL[4][128];
  __shared__ float csL[4];
  const int lane = threadIdx.x & 63;
  const int wid = threadIdx.x >> 6;
  const int w = blockIdx.x * 4 + wid;
  const int f = w >> 1, h = w & 1;
  const int lstride = flags[0];
  const int mstride = flags[1];

  int idx = -1, valid = 0;
  if (lane < 32) {
    idx = (int)loopw[(size_t)(f * 32 + lane) * lstride];
    valid = maskb[(size_t)f * mstride] ? 1 : 0;
  }
#pragma unroll
  for (int j = 0; j < 32; ++j) {
    int oidx = __shfl(idx, j);
    if (lane < 32 && j < lane && oidx == idx) valid = 0;
  }

  const size_t qb = (size_t)f * kD + h * kDH + 2 * lane;
  const float qa = (float)Q[qb];
  const float qbv = (float)Q[qb + 1];
  float s0 = 0.0f, cv0 = 0.0f, cv1 = 0.0f;
  for (int e = 0; e < 32; ++e) {
    int ei = __shfl(idx, e);
    int ev = __shfl(valid, e);
    if (!ev) continue;
    size_t kb = (size_t)ei * kD + h * kDH + 2 * lane;
    float part = qa * (float)Km[kb] + qbv * (float)Km[kb + 1];
#pragma unroll
    for (int m = 1; m < 64; m <<= 1) part += __shfl_xor(part, m);
    float pe = __expf(part * kScale);
    s0 += pe;
    cv0 += pe * (float)V[kb];
    cv1 += pe * (float)V[kb + 1];
  }
  cvL[wid][2 * lane] = cv0;
  cvL[wid][2 * lane + 1] = cv1;
  if (lane == 0) csL[wid] = s0;
  __syncthreads();

  // combine: 2 faces x 256 cols, 2 outputs/thread
#pragma unroll
  for (int e = 0; e < 2; ++e) {
    int idx2 = e * 256 + threadIdx.x;
    int floc = idx2 >> 8;
    int c = idx2 & 255;
    int h2 = c >> 7;
    int d = c & 127;
    int widx = floc * 2 + h2;
    int fabs_ = blockIdx.x * 2 + floc;
    float n = -cvL[widx][d];
    float dn = -csL[widx];
#pragma unroll
    for (int z = 0; z < kNS; ++z) {
      n += (float)numb[((size_t)(z * kH + h2) * kL + fabs_) * kDH + d];
      dn += denb[(size_t)(z * kH + h2) * kL + fabs_];
    }
    out16[(size_t)fabs_ * kD + h2 * kDH + d] = (f16)(n / dn);
  }
}

extern "C" void kernel_launch(void* const* d_in, const int* in_sizes, int n_in,
                              void* d_out, int out_size, void* d_ws, size_t ws_size,
                              hipStream_t stream) {
  const unsigned int* loopw = (const unsigned int*)d_in[0];
  const unsigned char* fmask = (const unsigned char*)d_in[1];
  const float* edge = (const float*)d_in[2];
  const float* face = (const float*)d_in[3];
  const float* inw = (const float*)d_in[4];
  const float* inb = (const float*)d_in[5];
  const float* outw = (const float*)d_in[6];
  const float* outb = (const float*)d_in[7];
  float* out = (float*)d_out;

  char* p = (char*)d_ws;
  auto alloc = [&](size_t bytes) {
    char* q = p;
    p += (bytes + 255) & ~(size_t)255;
    return q;
  };
  int* flags = (int*)alloc(256);
  f16* e16 = (f16*)alloc((size_t)kS * kD * 2);
  f16* win16 = (f16*)alloc((size_t)kNL * 3 * kD * kD * 2);
  f16* wout16 = (f16*)alloc((size_t)kNL * kD * kD * 2);
  f16* xa = (f16*)alloc((size_t)kL * kD * 2);
  f16* xb = (f16*)alloc((size_t)kL * kD * 2);
  f16* q16 = (f16*)alloc((size_t)kL * kD * 2);
  f16* k16 = (f16*)alloc((size_t)kS * kD * 2);
  f16* v16 = (f16*)alloc((size_t)kS * kD * 2);
  f16* vt16 = (f16*)alloc((size_t)kS * kD * 2);
  f16* ao16 = (f16*)alloc((size_t)kL * kD * 2);
  f16* numb = (f16*)alloc((size_t)kNS * kH * kL * kDH * 2);
  float* denb = (float*)alloc((size_t)kNS * kH * kL * 4);

  detect_k<<<1, 256, 0, stream>>>(loopw, fmask, flags);
  cvt_all_k<<<1024, 256, 0, stream>>>(edge, face, inw, outw, e16, xa, win16,
                                      wout16);

  f16* x = xa;
  f16* xn = xb;
  for (int l = 0; l < kNL; ++l) {
    const f16* wql = win16 + (size_t)l * 3 * kD * kD;
    qkv_gemm_k<<<1280, 256, 0, stream>>>(x, e16, wql, inb + l * 3 * kD, q16,
                                         k16, vt16, v16);
    attn_dense3_k<<<dim3(kL / 128, kH, kNS), 256, 0, stream>>>(q16, k16, vt16,
                                                               numb, denb);
    corrcomb_k<<<kL / 2, 256, 0, stream>>>(loopw, fmask, flags, q16, k16, v16,
                                           numb, denb, ao16);
    gemm_awt_k<<<dim3(kL / 64, kD / 64), 256, 0, stream>>>(
        ao16, wout16 + (size_t)l * kD * kD, outb + l * kD, xn,
        (l == kNL - 1) ? out : nullptr, kL, kD, kD);
    f16* tmp = x;
    x = xn;
    xn = tmp;
  }
}